// Round 5
// baseline (570.077 us; speedup 1.0000x reference)
//
#include <hip/hip_runtime.h>

#define BS 256
#define NB1 2048   // reduction blocks (8/CU)
#define NB3 2048   // add blocks

typedef float vfloat4 __attribute__((ext_vector_type(4)));

// Pass 1 + fused finish: per-block weighted column partials, then the LAST
// block to finish (device-scope ticket) reduces all partials and computes
// r = W_out @ relu(W_in @ avg). No grid-wide spin, no acquire fence on the
// hot path (R4 lesson: coop grid.sync + L2-invalidating fences cost ~200us).
__global__ void __launch_bounds__(BS) reduce_fused(
    const float* __restrict__ x, const float* __restrict__ w,
    const float* __restrict__ W_in, const float* __restrict__ W_out,
    float* __restrict__ colpart, float* __restrict__ wpart,
    float* __restrict__ r_out, unsigned int* __restrict__ counter,
    long long total4) {
  const int tid = threadIdx.x;
  const long long stride2 = (long long)gridDim.x * (2 * BS);
  const vfloat4* x4 = (const vfloat4*)x;
  __shared__ vfloat4 sacc[BS];
  __shared__ float   sw[BS];

  // ---- weighted column reduction over this block's chunks ----
  {
    vfloat4 a0 = (vfloat4)(0.f), a1 = (vfloat4)(0.f);
    float w0 = 0.f, w1 = 0.f;
    long long c = (long long)blockIdx.x * (2 * BS) + tid;
    for (; c + BS < total4; c += stride2) {
      const float wi0 = w[(int)(c >> 3)];
      const float wi1 = w[(int)((c + BS) >> 3)];
      a0 += wi0 * x4[c];
      a1 += wi1 * x4[c + BS];
      w0 += wi0; w1 += wi1;
    }
    if (c < total4) {
      const float wi = w[(int)(c >> 3)];
      a0 += wi * x4[c];
      w0 += wi;
    }
    a0 += a1; w0 += w1;
    sacc[tid] = a0;
    sw[tid] = w0;
  }
  __syncthreads();
  for (int s = BS / 2; s >= 8; s >>= 1) {  // keep column groups (tid&7) apart
    if (tid < s) {
      sacc[tid] += sacc[tid + s];
      sw[tid] += sw[tid + s];
    }
    __syncthreads();
  }
  if (tid < 8) {
    ((vfloat4*)(colpart + (long long)blockIdx.x * 32))[tid] = sacc[tid];
  }
  if (tid == 0) {
    wpart[blockIdx.x] = sw[0] + sw[1] + sw[2] + sw[3] +
                        sw[4] + sw[5] + sw[6] + sw[7];
  }

  // ---- last-block-done ticket ----
  __shared__ unsigned int sticket;
  __threadfence();  // release: partials visible before ticket increment
  if (tid == 0) sticket = atomicAdd(counter, 1u);
  __syncthreads();
  if (sticket != (unsigned int)(gridDim.x - 1)) return;
  __threadfence();  // acquire: all other blocks' partials now visible

  // ---- finish: reduce partials, r = W_out @ relu(W_in @ avg) ----
  __shared__ float avg[32];
  __shared__ float h[128];
  {
    const vfloat4* cp4 = (const vfloat4*)colpart;
    vfloat4 acc = (vfloat4)(0.f);
    for (int cb = tid; cb < NB1 * 8; cb += BS) acc += cp4[cb];  // quad=tid&7
    sacc[tid] = acc;
    const vfloat4* wp4 = (const vfloat4*)wpart;
    float s = 0.f;
    for (int cb = tid; cb < NB1 / 4; cb += BS) {
      vfloat4 v = wp4[cb];
      s += v.x + v.y + v.z + v.w;
    }
    sw[tid] = s;
  }
  __syncthreads();
  for (int s = BS / 2; s >= 8; s >>= 1) {
    if (tid < s) {
      sacc[tid] += sacc[tid + s];
      sw[tid] += sw[tid + s];
    }
    __syncthreads();
  }
  if (tid == 0) {
    // wpart counted each w 8x (once per chunk) -> *0.125 (exact)
    sw[0] = (sw[0] + sw[1] + sw[2] + sw[3] +
             sw[4] + sw[5] + sw[6] + sw[7]) * 0.125f;
  }
  __syncthreads();
  if (tid < 32) {
    const float* sflat = (const float*)sacc;  // column j = sacc[j>>2][j&3]
    avg[tid] = sflat[tid] / sw[0];
  }
  __syncthreads();
  if (tid < 128) {
    float a = 0.f;
    for (int k = 0; k < 32; ++k) a = fmaf(W_in[tid * 32 + k], avg[k], a);
    h[tid] = fmaxf(a, 0.f);
  }
  __syncthreads();
  if (tid < 32) {
    float r = 0.f;
    for (int k = 0; k < 128; ++k) r = fmaf(W_out[tid * 128 + k], h[k], r);
    r_out[tid] = r;
  }
}

// Pass 2: out = x + r; x read regular (L2/L3-warm), out via NT stores.
__global__ void __launch_bounds__(BS) add_kernel(
    const float* __restrict__ x, const float* __restrict__ r,
    float* __restrict__ out, long long total4) {
  const int tid = threadIdx.x;
  const vfloat4 rr = ((const vfloat4*)r)[tid & 7];  // chunk col-quad == tid&7
  const long long stride2 = (long long)gridDim.x * (2 * BS);
  const vfloat4* x4 = (const vfloat4*)x;
  vfloat4* o4 = (vfloat4*)out;
  long long c = (long long)blockIdx.x * (2 * BS) + tid;
  for (; c + BS < total4; c += stride2) {
    vfloat4 v0 = x4[c] + rr;
    vfloat4 v1 = x4[c + BS] + rr;
    __builtin_nontemporal_store(v0, &o4[c]);
    __builtin_nontemporal_store(v1, &o4[c + BS]);
  }
  if (c < total4) {
    vfloat4 v = x4[c] + rr;
    __builtin_nontemporal_store(v, &o4[c]);
  }
}

extern "C" void kernel_launch(void* const* d_in, const int* in_sizes, int n_in,
                              void* d_out, int out_size, void* d_ws, size_t ws_size,
                              hipStream_t stream) {
  const float* x     = (const float*)d_in[0];
  const float* w     = (const float*)d_in[1];
  const float* W_in  = (const float*)d_in[2];
  const float* W_out = (const float*)d_in[3];
  float* out = (float*)d_out;

  const long long N = (long long)in_sizes[0] / 32;
  const long long total4 = N * 8;  // float4 chunks (32 floats/row)

  // ws layout: colpart[NB1*32] | wpart[NB1] | r[32] | counter (all 16B-aligned)
  float* colpart = (float*)d_ws;
  float* wpart   = colpart + (size_t)NB1 * 32;
  float* r       = wpart + NB1;
  unsigned int* counter = (unsigned int*)(r + 32);

  hipMemsetAsync((void*)counter, 0, sizeof(unsigned int), stream);
  reduce_fused<<<NB1, BS, 0, stream>>>(x, w, W_in, W_out, colpart, wpart, r,
                                       counter, total4);
  add_kernel<<<NB3, BS, 0, stream>>>(x, r, out, total4);
}

// Round 6
// 275.575 us; speedup vs baseline: 2.0687x; 2.0687x over previous
//
#include <hip/hip_runtime.h>

#define BS 256
#define NB1 2048   // reduction blocks (8/CU)
#define NB3 2048   // add blocks

typedef float vfloat4 __attribute__((ext_vector_type(4)));

// Pass 1: weighted column sums via per-block LDS reduction + 33 relaxed
// device-scope atomicAdds into zeroed ws accumulators. NO fences, NO tickets
// (R5 lesson: per-block agent-scope __threadfence => L2 wb/inv per block =
// +300us). Cross-kernel visibility comes from the dispatch boundary.
// gw accumulates 8x sum(w) (w counted once per float4 chunk); /8 later.
__global__ void __launch_bounds__(BS) reduce_atomic(
    const float* __restrict__ x, const float* __restrict__ w,
    float* __restrict__ gacc, float* __restrict__ gw, long long total4) {
  const int tid = threadIdx.x;
  const long long stride2 = (long long)gridDim.x * (2 * BS);
  const vfloat4* x4 = (const vfloat4*)x;
  __shared__ vfloat4 sacc[BS];
  __shared__ float   sw[BS];
  {
    vfloat4 a0 = (vfloat4)(0.f), a1 = (vfloat4)(0.f);
    float w0 = 0.f, w1 = 0.f;
    long long c = (long long)blockIdx.x * (2 * BS) + tid;
    for (; c + BS < total4; c += stride2) {
      const float wi0 = w[(int)(c >> 3)];
      const float wi1 = w[(int)((c + BS) >> 3)];
      a0 += wi0 * x4[c];
      a1 += wi1 * x4[c + BS];
      w0 += wi0; w1 += wi1;
    }
    if (c < total4) {
      const float wi = w[(int)(c >> 3)];
      a0 += wi * x4[c];
      w0 += wi;
    }
    a0 += a1; w0 += w1;
    sacc[tid] = a0;
    sw[tid] = w0;
  }
  __syncthreads();
  for (int s = BS / 2; s >= 8; s >>= 1) {  // keep column groups (tid&7) apart
    if (tid < s) {
      sacc[tid] += sacc[tid + s];
      sw[tid] += sw[tid + s];
    }
    __syncthreads();
  }
  // column j's block-partial = ((float*)sacc)[j]
  if (tid < 32) atomicAdd(&gacc[tid], ((const float*)sacc)[tid]);
  if (tid == 0) {
    atomicAdd(gw, sw[0] + sw[1] + sw[2] + sw[3] +
                  sw[4] + sw[5] + sw[6] + sw[7]);
  }
}

// Pass 2: every block redundantly computes r = W_out @ relu(W_in @ avg)
// (20 KB weights, L2-warm; ~8K FLOP — sub-us), then out = x + r with NT
// stores. x is IF-warm from pass 1.
__global__ void __launch_bounds__(BS) add_kernel(
    const float* __restrict__ x, const float* __restrict__ gacc,
    const float* __restrict__ gw, const float* __restrict__ W_in,
    const float* __restrict__ W_out, float* __restrict__ out,
    long long total4) {
  const int tid = threadIdx.x;
  __shared__ float avg[32];
  __shared__ float h[128];
  __shared__ float rsh[32];
  if (tid < 32) avg[tid] = gacc[tid] / (gw[0] * 0.125f);
  __syncthreads();
  if (tid < 128) {
    float a = 0.f;
    for (int k = 0; k < 32; ++k) a = fmaf(W_in[tid * 32 + k], avg[k], a);
    h[tid] = fmaxf(a, 0.f);
  }
  __syncthreads();
  if (tid < 32) {
    float r = 0.f;
    for (int k = 0; k < 128; ++k) r = fmaf(W_out[tid * 128 + k], h[k], r);
    rsh[tid] = r;
  }
  __syncthreads();
  const vfloat4 rr = ((const vfloat4*)rsh)[tid & 7];  // chunk col-quad = tid&7
  const long long stride2 = (long long)gridDim.x * (2 * BS);
  const vfloat4* x4 = (const vfloat4*)x;
  vfloat4* o4 = (vfloat4*)out;
  long long c = (long long)blockIdx.x * (2 * BS) + tid;
  for (; c + BS < total4; c += stride2) {
    vfloat4 v0 = x4[c] + rr;
    vfloat4 v1 = x4[c + BS] + rr;
    __builtin_nontemporal_store(v0, &o4[c]);
    __builtin_nontemporal_store(v1, &o4[c + BS]);
  }
  if (c < total4) {
    vfloat4 v = x4[c] + rr;
    __builtin_nontemporal_store(v, &o4[c]);
  }
}

extern "C" void kernel_launch(void* const* d_in, const int* in_sizes, int n_in,
                              void* d_out, int out_size, void* d_ws, size_t ws_size,
                              hipStream_t stream) {
  const float* x     = (const float*)d_in[0];
  const float* w     = (const float*)d_in[1];
  const float* W_in  = (const float*)d_in[2];
  const float* W_out = (const float*)d_in[3];
  float* out = (float*)d_out;

  const long long N = (long long)in_sizes[0] / 32;
  const long long total4 = N * 8;  // float4 chunks (32 floats/row)

  // ws layout: gacc[32] | gw[1] — zeroed each call (atomic accumulators)
  float* gacc = (float*)d_ws;
  float* gw   = gacc + 32;
  hipMemsetAsync((void*)gacc, 0, 33 * sizeof(float), stream);

  reduce_atomic<<<NB1, BS, 0, stream>>>(x, w, gacc, gw, total4);
  add_kernel<<<NB3, BS, 0, stream>>>(x, gacc, gw, W_in, W_out, out, total4);
}